// Round 2
// baseline (304.442 us; speedup 1.0000x reference)
//
#include <hip/hip_runtime.h>

// LogicLayer forward, float32 in/out (reference dtypes: x f32, weights f32,
// idx int32; output f32 — harness compares at bf16 granularity).
//
// out[i,j] = sum_g softmax(W[j,:])[g] * gate_g(a,b), a=x[i,idx_a[j]], b=x[i,idx_b[j]]
// The 16-gate mixture is affine in {1, a, b, a*b}:
//   out = C0 + Ca*a + Cb*b + Cab*(a*b)
// with (p = softmax probs):
//   C0  = p8+p9+p10+p11+p12+p13+p14+p15
//   Ca  = p2+p3+p6+p7-p8-p9-p12-p13
//   Cb  = p4+p5+p6+p7-p8-p9-p10-p11
//   Cab = p1-p2-p4-2p6-p7+p8+2p9+p11+p13-p14
// Coefficients recomputed per block (redundancy over row-chunks) to avoid
// workspace dependency; cost amortized over ROWS_PER_BLOCK rows.

#define THREADS 256
#define JPT 4                      // output columns per thread
#define TILE_J (THREADS * JPT)     // 1024 columns per block
#define ROWS_PER_BLOCK 32

__global__ __launch_bounds__(THREADS) void logic_fwd(
    const float* __restrict__ x,
    const float* __restrict__ w,
    const int* __restrict__ idx_a,
    const int* __restrict__ idx_b,
    float* __restrict__ out,
    int B, int IN_DIM, int OUT_DIM)
{
    const int j0 = blockIdx.x * TILE_J + threadIdx.x * JPT;
    if (j0 + JPT > OUT_DIM) return;

    float c0[JPT], ca[JPT], cb[JPT], cab[JPT];
    int ia[JPT], ib[JPT];

    // ---- prologue: softmax -> affine coefficients for this thread's columns
    #pragma unroll
    for (int k = 0; k < JPT; ++k) {
        const int j = j0 + k;
        ia[k] = idx_a[j];
        ib[k] = idx_b[j];

        // 16 f32 weights = 64 B, four float4 loads
        float wv[16];
        const float4* wp = reinterpret_cast<const float4*>(w + (size_t)j * 16);
        #pragma unroll
        for (int q = 0; q < 4; ++q) {
            float4 v = wp[q];
            wv[q * 4 + 0] = v.x;
            wv[q * 4 + 1] = v.y;
            wv[q * 4 + 2] = v.z;
            wv[q * 4 + 3] = v.w;
        }

        float m = -1e30f;
        #pragma unroll
        for (int g = 0; g < 16; ++g) m = fmaxf(m, wv[g]);

        float e[16];
        float s = 0.f;
        #pragma unroll
        for (int g = 0; g < 16; ++g) {
            e[g] = __expf(wv[g] - m);
            s += e[g];
        }
        const float inv = 1.f / s;

        const float C0  = e[8] + e[9] + e[10] + e[11] + e[12] + e[13] + e[14] + e[15];
        const float Ca  = e[2] + e[3] + e[6] + e[7] - e[8] - e[9] - e[12] - e[13];
        const float Cb  = e[4] + e[5] + e[6] + e[7] - e[8] - e[9] - e[10] - e[11];
        const float Cab = e[1] - e[2] - e[4] - 2.f * e[6] - e[7]
                        + e[8] + 2.f * e[9] + e[11] + e[13] - e[14];

        c0[k]  = C0  * inv;
        ca[k]  = Ca  * inv;
        cb[k]  = Cb  * inv;
        cab[k] = Cab * inv;
    }

    // ---- main loop over batch rows
    const int r0 = blockIdx.y * ROWS_PER_BLOCK;
    #pragma unroll 1
    for (int r = 0; r < ROWS_PER_BLOCK; ++r) {
        const int i = r0 + r;
        if (i >= B) break;
        const float* __restrict__ xrow = x + (size_t)i * IN_DIM;

        float4 pack;
        float res[JPT];
        #pragma unroll
        for (int k = 0; k < JPT; ++k) {
            const float a = xrow[ia[k]];
            const float b = xrow[ib[k]];
            float v = c0[k];
            v = fmaf(a, ca[k], v);
            v = fmaf(b, cb[k], v);
            v = fmaf(a * b, cab[k], v);
            res[k] = v;
        }
        pack.x = res[0]; pack.y = res[1]; pack.z = res[2]; pack.w = res[3];
        *reinterpret_cast<float4*>(out + (size_t)i * OUT_DIM + j0) = pack;
    }
}

extern "C" void kernel_launch(void* const* d_in, const int* in_sizes, int n_in,
                              void* d_out, int out_size, void* d_ws, size_t ws_size,
                              hipStream_t stream) {
    const float* x     = (const float*)d_in[0];
    const float* w     = (const float*)d_in[1];
    const int*   idx_a = (const int*)d_in[2];
    const int*   idx_b = (const int*)d_in[3];
    float*       out   = (float*)d_out;

    const int OUT_DIM = in_sizes[2];            // 16384
    const int B       = out_size / OUT_DIM;     // 2048
    const int IN_DIM  = in_sizes[0] / B;        // 8192

    dim3 grid((OUT_DIM + TILE_J - 1) / TILE_J,
              (B + ROWS_PER_BLOCK - 1) / ROWS_PER_BLOCK);
    logic_fwd<<<grid, dim3(THREADS), 0, stream>>>(x, w, idx_a, idx_b, out,
                                                  B, IN_DIM, OUT_DIM);
}

// Round 3
// 223.603 us; speedup vs baseline: 1.3615x; 1.3615x over previous
//
#include <hip/hip_runtime.h>

// LogicLayer forward, float32 in/out.
// out[i,j] = C0[j] + Ca[j]*a + Cb[j]*b + Cab[j]*(a*b),
//   a = x[i, idx_a[j]], b = x[i, idx_b[j]],
// where the C's are the affine collapse of the 16-gate softmax mixture.
//
// Two-kernel structure:
//   1) coeffs_k: per-column softmax -> float4 {C0,Ca,Cb,Cab} into d_ws (256 KB).
//   2) row_k: one block per batch row. Stage the 32 KB x-row into LDS
//      (coalesced, HBM-fetched exactly once), then gather from LDS.
//      Coeff/idx reads are coalesced and L2-resident.

#define THREADS 256
#define IN_DIM_MAX 8192   // problem shape: IN_DIM = 8192 (32 KB LDS)

__global__ __launch_bounds__(THREADS) void coeffs_k(
    const float* __restrict__ w,
    float4* __restrict__ cf,
    int OUT_DIM)
{
    const int j = blockIdx.x * THREADS + threadIdx.x;
    if (j >= OUT_DIM) return;

    float wv[16];
    const float4* wp = reinterpret_cast<const float4*>(w + (size_t)j * 16);
    #pragma unroll
    for (int q = 0; q < 4; ++q) {
        float4 v = wp[q];
        wv[q * 4 + 0] = v.x;
        wv[q * 4 + 1] = v.y;
        wv[q * 4 + 2] = v.z;
        wv[q * 4 + 3] = v.w;
    }

    float m = -1e30f;
    #pragma unroll
    for (int g = 0; g < 16; ++g) m = fmaxf(m, wv[g]);

    float e[16];
    float s = 0.f;
    #pragma unroll
    for (int g = 0; g < 16; ++g) {
        e[g] = __expf(wv[g] - m);
        s += e[g];
    }
    const float inv = 1.f / s;

    const float C0  = e[8] + e[9] + e[10] + e[11] + e[12] + e[13] + e[14] + e[15];
    const float Ca  = e[2] + e[3] + e[6] + e[7] - e[8] - e[9] - e[12] - e[13];
    const float Cb  = e[4] + e[5] + e[6] + e[7] - e[8] - e[9] - e[10] - e[11];
    const float Cab = e[1] - e[2] - e[4] - 2.f * e[6] - e[7]
                    + e[8] + 2.f * e[9] + e[11] + e[13] - e[14];

    cf[j] = make_float4(C0 * inv, Ca * inv, Cb * inv, Cab * inv);
}

__global__ __launch_bounds__(THREADS) void row_k(
    const float* __restrict__ x,
    const float4* __restrict__ cf,
    const int4* __restrict__ ia4,
    const int4* __restrict__ ib4,
    float4* __restrict__ out4,
    int IN_DIM, int OUT_DIM)
{
    __shared__ float sx[IN_DIM_MAX];

    const int row = blockIdx.x;
    const int tid = threadIdx.x;

    // ---- stage the x row into LDS, coalesced float4
    {
        const float4* xr4 = reinterpret_cast<const float4*>(x + (size_t)row * IN_DIM);
        float4* s4 = reinterpret_cast<float4*>(sx);
        const int n4 = IN_DIM / 4;
        #pragma unroll 2
        for (int t = tid; t < n4; t += THREADS) s4[t] = xr4[t];
    }
    __syncthreads();

    float4* __restrict__ orow = out4 + (size_t)row * (OUT_DIM / 4);
    const int nchunk = OUT_DIM / (THREADS * 4);

    #pragma unroll 2
    for (int c = 0; c < nchunk; ++c) {
        const int j4 = c * THREADS + tid;   // index in 4-column units
        const int j  = j4 * 4;

        const int4 va = ia4[j4];
        const int4 vb = ib4[j4];
        const float4 f0 = cf[j + 0];
        const float4 f1 = cf[j + 1];
        const float4 f2 = cf[j + 2];
        const float4 f3 = cf[j + 3];

        float4 r;
        {
            const float a = sx[va.x], b = sx[vb.x];
            r.x = fmaf(a * b, f0.w, fmaf(b, f0.z, fmaf(a, f0.y, f0.x)));
        }
        {
            const float a = sx[va.y], b = sx[vb.y];
            r.y = fmaf(a * b, f1.w, fmaf(b, f1.z, fmaf(a, f1.y, f1.x)));
        }
        {
            const float a = sx[va.z], b = sx[vb.z];
            r.z = fmaf(a * b, f2.w, fmaf(b, f2.z, fmaf(a, f2.y, f2.x)));
        }
        {
            const float a = sx[va.w], b = sx[vb.w];
            r.w = fmaf(a * b, f3.w, fmaf(b, f3.z, fmaf(a, f3.y, f3.x)));
        }
        orow[j4] = r;
    }
}

extern "C" void kernel_launch(void* const* d_in, const int* in_sizes, int n_in,
                              void* d_out, int out_size, void* d_ws, size_t ws_size,
                              hipStream_t stream) {
    const float* x     = (const float*)d_in[0];
    const float* w     = (const float*)d_in[1];
    const int*   idx_a = (const int*)d_in[2];
    const int*   idx_b = (const int*)d_in[3];
    float*       out   = (float*)d_out;

    const int OUT_DIM = in_sizes[2];            // 16384
    const int B       = out_size / OUT_DIM;     // 2048
    const int IN_DIM  = in_sizes[0] / B;        // 8192

    float4* cf = (float4*)d_ws;                 // OUT_DIM * 16 B = 256 KB

    coeffs_k<<<(OUT_DIM + THREADS - 1) / THREADS, THREADS, 0, stream>>>(
        w, cf, OUT_DIM);

    row_k<<<B, THREADS, 0, stream>>>(
        x, cf,
        reinterpret_cast<const int4*>(idx_a),
        reinterpret_cast<const int4*>(idx_b),
        reinterpret_cast<float4*>(out),
        IN_DIM, OUT_DIM);
}

// Round 4
// 201.502 us; speedup vs baseline: 1.5109x; 1.1097x over previous
//
#include <hip/hip_runtime.h>

// LogicLayer forward, float32 in/out.
// out[i,j] = C0[j] + Ca[j]*a + Cb[j]*b + Cab[j]*(a*b),
//   a = x[i, idx_a[j]], b = x[i, idx_b[j]]  (affine collapse of 16-gate softmax).
//
// Structure:
//   1) coeffs_k: per-column softmax -> SoA coeff arrays in d_ws (4 * OUT_DIM f32).
//   2) row_k: one block per 2 batch rows. Stage 64 KB (2 rows) of x into LDS
//      (one contiguous coalesced copy, HBM-read exactly once), then sweep
//      columns with a software-pipelined loop: prefetch next chunk's idx/coeffs
//      into registers while gathering/computing the current chunk for both rows.

#define THREADS 256
#define ROWS 2
#define IN_DIM_C 8192              // problem shape (32 KB/row in LDS)

__global__ __launch_bounds__(THREADS) void coeffs_k(
    const float* __restrict__ w,
    float* __restrict__ c0o, float* __restrict__ cao,
    float* __restrict__ cbo, float* __restrict__ cabo,
    int OUT_DIM)
{
    const int j = blockIdx.x * THREADS + threadIdx.x;
    if (j >= OUT_DIM) return;

    float wv[16];
    const float4* wp = reinterpret_cast<const float4*>(w + (size_t)j * 16);
    #pragma unroll
    for (int q = 0; q < 4; ++q) {
        float4 v = wp[q];
        wv[q * 4 + 0] = v.x; wv[q * 4 + 1] = v.y;
        wv[q * 4 + 2] = v.z; wv[q * 4 + 3] = v.w;
    }

    float m = -1e30f;
    #pragma unroll
    for (int g = 0; g < 16; ++g) m = fmaxf(m, wv[g]);

    float e[16]; float s = 0.f;
    #pragma unroll
    for (int g = 0; g < 16; ++g) { e[g] = __expf(wv[g] - m); s += e[g]; }
    const float inv = 1.f / s;

    const float C0  = e[8] + e[9] + e[10] + e[11] + e[12] + e[13] + e[14] + e[15];
    const float Ca  = e[2] + e[3] + e[6] + e[7] - e[8] - e[9] - e[12] - e[13];
    const float Cb  = e[4] + e[5] + e[6] + e[7] - e[8] - e[9] - e[10] - e[11];
    const float Cab = e[1] - e[2] - e[4] - 2.f * e[6] - e[7]
                    + e[8] + 2.f * e[9] + e[11] + e[13] - e[14];

    c0o[j]  = C0  * inv;
    cao[j]  = Ca  * inv;
    cbo[j]  = Cb  * inv;
    cabo[j] = Cab * inv;
}

__global__ __launch_bounds__(THREADS) void row_k(
    const float* __restrict__ x,
    const float4* __restrict__ c04, const float4* __restrict__ ca4,
    const float4* __restrict__ cb4, const float4* __restrict__ cab4,
    const int4* __restrict__ ia4,
    const int4* __restrict__ ib4,
    float4* __restrict__ out4,
    int IN_DIM, int OUT_DIM)
{
    __shared__ float sx[ROWS * IN_DIM_C];

    const int row0 = blockIdx.x * ROWS;
    const int tid  = threadIdx.x;
    const int nchunk = OUT_DIM / (THREADS * 4);   // 16

    // ---- prefetch chunk 0's idx/coeffs (overlaps with staging below)
    int4   va = ia4[tid];
    int4   vb = ib4[tid];
    float4 f0 = c04[tid], fa = ca4[tid], fb = cb4[tid], fc = cab4[tid];

    // ---- stage ROWS contiguous x rows into LDS (one coalesced 64 KB copy)
    {
        const float4* xr4 = reinterpret_cast<const float4*>(x + (size_t)row0 * IN_DIM);
        float4* s4 = reinterpret_cast<float4*>(sx);
        const int n4 = ROWS * IN_DIM / 4;          // 4096
        #pragma unroll
        for (int t = tid; t < n4; t += THREADS) s4[t] = xr4[t];
    }
    __syncthreads();

    const int o4 = OUT_DIM / 4;
    float4* __restrict__ orow0 = out4 + (size_t)row0 * o4;
    float4* __restrict__ orow1 = orow0 + o4;

    #pragma unroll 1
    for (int c = 0; c < nchunk; ++c) {
        // consume current regs
        const int4   cva = va, cvb = vb;
        const float4 g0 = f0, ga = fa, gb = fb, gc = fc;
        const int j4 = c * THREADS + tid;

        // prefetch next chunk while we gather/compute
        if (c + 1 < nchunk) {
            const int nj4 = j4 + THREADS;
            va = ia4[nj4]; vb = ib4[nj4];
            f0 = c04[nj4]; fa = ca4[nj4]; fb = cb4[nj4]; fc = cab4[nj4];
        }

        float4 r0, r1;
        // row 0
        {
            const float a0 = sx[cva.x], b0 = sx[cvb.x];
            const float a1 = sx[cva.y], b1 = sx[cvb.y];
            const float a2 = sx[cva.z], b2 = sx[cvb.z];
            const float a3 = sx[cva.w], b3 = sx[cvb.w];
            r0.x = fmaf(a0 * b0, gc.x, fmaf(b0, gb.x, fmaf(a0, ga.x, g0.x)));
            r0.y = fmaf(a1 * b1, gc.y, fmaf(b1, gb.y, fmaf(a1, ga.y, g0.y)));
            r0.z = fmaf(a2 * b2, gc.z, fmaf(b2, gb.z, fmaf(a2, ga.z, g0.z)));
            r0.w = fmaf(a3 * b3, gc.w, fmaf(b3, gb.w, fmaf(a3, ga.w, g0.w)));
        }
        // row 1 (independent chain — LDS offset IN_DIM_C)
        {
            const float a0 = sx[IN_DIM_C + cva.x], b0 = sx[IN_DIM_C + cvb.x];
            const float a1 = sx[IN_DIM_C + cva.y], b1 = sx[IN_DIM_C + cvb.y];
            const float a2 = sx[IN_DIM_C + cva.z], b2 = sx[IN_DIM_C + cvb.z];
            const float a3 = sx[IN_DIM_C + cva.w], b3 = sx[IN_DIM_C + cvb.w];
            r1.x = fmaf(a0 * b0, gc.x, fmaf(b0, gb.x, fmaf(a0, ga.x, g0.x)));
            r1.y = fmaf(a1 * b1, gc.y, fmaf(b1, gb.y, fmaf(a1, ga.y, g0.y)));
            r1.z = fmaf(a2 * b2, gc.z, fmaf(b2, gb.z, fmaf(a2, ga.z, g0.z)));
            r1.w = fmaf(a3 * b3, gc.w, fmaf(b3, gb.w, fmaf(a3, ga.w, g0.w)));
        }
        orow0[j4] = r0;
        orow1[j4] = r1;
    }
}

extern "C" void kernel_launch(void* const* d_in, const int* in_sizes, int n_in,
                              void* d_out, int out_size, void* d_ws, size_t ws_size,
                              hipStream_t stream) {
    const float* x     = (const float*)d_in[0];
    const float* w     = (const float*)d_in[1];
    const int*   idx_a = (const int*)d_in[2];
    const int*   idx_b = (const int*)d_in[3];
    float*       out   = (float*)d_out;

    const int OUT_DIM = in_sizes[2];            // 16384
    const int B       = out_size / OUT_DIM;     // 2048
    const int IN_DIM  = in_sizes[0] / B;        // 8192

    float* c0  = (float*)d_ws;                  // 4 * OUT_DIM floats = 256 KB
    float* ca  = c0 + OUT_DIM;
    float* cb  = ca + OUT_DIM;
    float* cab = cb + OUT_DIM;

    coeffs_k<<<(OUT_DIM + THREADS - 1) / THREADS, THREADS, 0, stream>>>(
        w, c0, ca, cb, cab, OUT_DIM);

    row_k<<<B / ROWS, THREADS, 0, stream>>>(
        x,
        reinterpret_cast<const float4*>(c0),
        reinterpret_cast<const float4*>(ca),
        reinterpret_cast<const float4*>(cb),
        reinterpret_cast<const float4*>(cab),
        reinterpret_cast<const int4*>(idx_a),
        reinterpret_cast<const int4*>(idx_b),
        reinterpret_cast<float4*>(out),
        IN_DIM, OUT_DIM);
}

// Round 6
// 193.369 us; speedup vs baseline: 1.5744x; 1.0421x over previous
//
#include <hip/hip_runtime.h>

// LogicLayer forward, float32 in/out.
// out[i,j] = C0[j] + Ca[j]*a + Cb[j]*b + Cab[j]*(a*b),
//   a = x[i, idx_a[j]], b = x[i, idx_b[j]]  (affine collapse of 16-gate softmax).
//
// Structure:
//   1) coeffs_k: per-column softmax -> SoA coeff arrays in d_ws.
//   2) row_k: one 512-thread block per 2 batch rows. The two rows are staged
//      INTERLEAVED in LDS (sx2[i] = {row0[i], row1[i]}, 64 KB) so each column
//      gather is a single ds_read_b64 serving both rows. 512-thread blocks
//      double resident waves (2 blocks/CU is LDS-pinned either way) -> 50%
//      occupancy. idx/coeff loads for chunk c+1 are prefetched into registers
//      while chunk c computes. Output stores are non-temporal (write-once);
//      NT stores use a native ext_vector_type since the builtin rejects
//      HIP_vector_type.

#define THREADS 512
#define CTHREADS 256
#define ROWS 2
#define IN_DIM_C 8192              // problem shape (2 rows -> 64 KB LDS)

typedef float floatx4 __attribute__((ext_vector_type(4)));

__global__ __launch_bounds__(CTHREADS) void coeffs_k(
    const float* __restrict__ w,
    float* __restrict__ c0o, float* __restrict__ cao,
    float* __restrict__ cbo, float* __restrict__ cabo,
    int OUT_DIM)
{
    const int j = blockIdx.x * CTHREADS + threadIdx.x;
    if (j >= OUT_DIM) return;

    float wv[16];
    const float4* wp = reinterpret_cast<const float4*>(w + (size_t)j * 16);
    #pragma unroll
    for (int q = 0; q < 4; ++q) {
        float4 v = wp[q];
        wv[q * 4 + 0] = v.x; wv[q * 4 + 1] = v.y;
        wv[q * 4 + 2] = v.z; wv[q * 4 + 3] = v.w;
    }

    float m = -1e30f;
    #pragma unroll
    for (int g = 0; g < 16; ++g) m = fmaxf(m, wv[g]);

    float e[16]; float s = 0.f;
    #pragma unroll
    for (int g = 0; g < 16; ++g) { e[g] = __expf(wv[g] - m); s += e[g]; }
    const float inv = 1.f / s;

    const float C0  = e[8] + e[9] + e[10] + e[11] + e[12] + e[13] + e[14] + e[15];
    const float Ca  = e[2] + e[3] + e[6] + e[7] - e[8] - e[9] - e[12] - e[13];
    const float Cb  = e[4] + e[5] + e[6] + e[7] - e[8] - e[9] - e[10] - e[11];
    const float Cab = e[1] - e[2] - e[4] - 2.f * e[6] - e[7]
                    + e[8] + 2.f * e[9] + e[11] + e[13] - e[14];

    c0o[j]  = C0  * inv;
    cao[j]  = Ca  * inv;
    cbo[j]  = Cb  * inv;
    cabo[j] = Cab * inv;
}

__global__ __launch_bounds__(THREADS) void row_k(
    const float* __restrict__ x,
    const float4* __restrict__ c04, const float4* __restrict__ ca4,
    const float4* __restrict__ cb4, const float4* __restrict__ cab4,
    const int4* __restrict__ ia4,
    const int4* __restrict__ ib4,
    float* __restrict__ out,
    int IN_DIM, int OUT_DIM)
{
    __shared__ float2 sx2[IN_DIM_C];   // interleaved: sx2[i] = {row0[i], row1[i]}

    const int row0 = blockIdx.x * ROWS;
    const int tid  = threadIdx.x;
    const int nchunk = OUT_DIM / (THREADS * 4);   // 8

    // ---- prefetch chunk 0's idx/coeffs (issued before staging loads complete)
    int4   va = ia4[tid];
    int4   vb = ib4[tid];
    float4 f0 = c04[tid], fa = ca4[tid], fb = cb4[tid], fc = cab4[tid];

    // ---- stage 2 rows interleaved into LDS (coalesced float4 in and out)
    {
        const float4* xr0 = reinterpret_cast<const float4*>(x + (size_t)row0 * IN_DIM);
        const float4* xr1 = reinterpret_cast<const float4*>(x + (size_t)(row0 + 1) * IN_DIM);
        float4* s4 = reinterpret_cast<float4*>(sx2);
        const int n4 = IN_DIM / 4;                 // 2048
        #pragma unroll
        for (int t = tid; t < n4; t += THREADS) {
            const float4 r0 = xr0[t];
            const float4 r1 = xr1[t];
            s4[2 * t + 0] = make_float4(r0.x, r1.x, r0.y, r1.y);
            s4[2 * t + 1] = make_float4(r0.z, r1.z, r0.w, r1.w);
        }
    }
    __syncthreads();

    floatx4* __restrict__ orow0 =
        reinterpret_cast<floatx4*>(out + (size_t)row0 * OUT_DIM);
    floatx4* __restrict__ orow1 =
        reinterpret_cast<floatx4*>(out + (size_t)(row0 + 1) * OUT_DIM);

    #pragma unroll 1
    for (int c = 0; c < nchunk; ++c) {
        const int4   cva = va, cvb = vb;
        const float4 g0 = f0, ga = fa, gb = fb, gc = fc;
        const int j4 = c * THREADS + tid;

        // prefetch next chunk while we gather/compute
        if (c + 1 < nchunk) {
            const int nj4 = j4 + THREADS;
            va = ia4[nj4]; vb = ib4[nj4];
            f0 = c04[nj4]; fa = ca4[nj4]; fb = cb4[nj4]; fc = cab4[nj4];
        }

        // one b64 gather per (column, operand) serves BOTH rows
        const float2 a0 = sx2[cva.x], b0 = sx2[cvb.x];
        const float2 a1 = sx2[cva.y], b1 = sx2[cvb.y];
        const float2 a2 = sx2[cva.z], b2 = sx2[cvb.z];
        const float2 a3 = sx2[cva.w], b3 = sx2[cvb.w];

        floatx4 r0, r1;
        r0.x = fmaf(a0.x * b0.x, gc.x, fmaf(b0.x, gb.x, fmaf(a0.x, ga.x, g0.x)));
        r0.y = fmaf(a1.x * b1.x, gc.y, fmaf(b1.x, gb.y, fmaf(a1.x, ga.y, g0.y)));
        r0.z = fmaf(a2.x * b2.x, gc.z, fmaf(b2.x, gb.z, fmaf(a2.x, ga.z, g0.z)));
        r0.w = fmaf(a3.x * b3.x, gc.w, fmaf(b3.x, gb.w, fmaf(a3.x, ga.w, g0.w)));

        r1.x = fmaf(a0.y * b0.y, gc.x, fmaf(b0.y, gb.x, fmaf(a0.y, ga.x, g0.x)));
        r1.y = fmaf(a1.y * b1.y, gc.y, fmaf(b1.y, gb.y, fmaf(a1.y, ga.y, g0.y)));
        r1.z = fmaf(a2.y * b2.y, gc.z, fmaf(b2.y, gb.z, fmaf(a2.y, ga.z, g0.z)));
        r1.w = fmaf(a3.y * b3.y, gc.w, fmaf(b3.y, gb.w, fmaf(a3.y, ga.w, g0.w)));

        __builtin_nontemporal_store(r0, &orow0[j4]);
        __builtin_nontemporal_store(r1, &orow1[j4]);
    }
}

extern "C" void kernel_launch(void* const* d_in, const int* in_sizes, int n_in,
                              void* d_out, int out_size, void* d_ws, size_t ws_size,
                              hipStream_t stream) {
    const float* x     = (const float*)d_in[0];
    const float* w     = (const float*)d_in[1];
    const int*   idx_a = (const int*)d_in[2];
    const int*   idx_b = (const int*)d_in[3];
    float*       out   = (float*)d_out;

    const int OUT_DIM = in_sizes[2];            // 16384
    const int B       = out_size / OUT_DIM;     // 2048
    const int IN_DIM  = in_sizes[0] / B;        // 8192

    float* c0  = (float*)d_ws;                  // 4 * OUT_DIM floats = 256 KB
    float* ca  = c0 + OUT_DIM;
    float* cb  = ca + OUT_DIM;
    float* cab = cb + OUT_DIM;

    coeffs_k<<<(OUT_DIM + CTHREADS - 1) / CTHREADS, CTHREADS, 0, stream>>>(
        w, c0, ca, cb, cab, OUT_DIM);

    row_k<<<B / ROWS, THREADS, 0, stream>>>(
        x,
        reinterpret_cast<const float4*>(c0),
        reinterpret_cast<const float4*>(ca),
        reinterpret_cast<const float4*>(cb),
        reinterpret_cast<const float4*>(cab),
        reinterpret_cast<const int4*>(idx_a),
        reinterpret_cast<const int4*>(idx_b),
        out,
        IN_DIM, OUT_DIM);
}